// Round 15
// baseline (146.277 us; speedup 1.0000x reference)
//
#include <hip/hip_runtime.h>
#include <hip/hip_bf16.h>
#include <stddef.h>

typedef __attribute__((ext_vector_type(8))) short short8;
typedef __attribute__((ext_vector_type(4))) short short4v;
typedef __attribute__((ext_vector_type(4))) unsigned short ushort4v;
typedef __attribute__((ext_vector_type(4))) float floatx4;
typedef __attribute__((ext_vector_type(2))) float floatx2;

#define N_ 4
#define C_ 256
#define H_ 128
#define W_ 128
#define HW_ (H_*W_)
#define NPX_ (N_*HW_)   // 65536
#define E_ 36      // k2*up2
#define OC_ 256

// round-to-nearest-even f32 -> bf16 bits
static __device__ __forceinline__ unsigned short f2bf(float f) {
    union { float f; unsigned u; } v; v.f = f;
    unsigned r = v.u + 0x7fff + ((v.u >> 16) & 1);
    return (unsigned short)(r >> 16);
}
static __device__ __forceinline__ float bf2f(unsigned short s) {
    union { unsigned u; float f; } v; v.u = ((unsigned)s) << 16;
    return v.f;
}

// ---------------- Kernel 0: build wcomb[320][256] bf16 (w_out ++ w_down) ; wBT[48][576] bf16 ----------------
__global__ __launch_bounds__(256) void k_prep(const float* __restrict__ wo,
                                              const float* __restrict__ wd,
                                              short* __restrict__ wcomb,
                                              const float* __restrict__ we,
                                              unsigned short* __restrict__ wBT) {
    int bx = blockIdx.x;
    if (bx < 80) {
        int i = (bx * 256 + threadIdx.x) * 4;   // < 81920
        int row = i >> 8, c = i & 255;
        const float* src = (row < 256) ? &wo[row * 256 + c] : &wd[(row - 256) * 256 + c];
        float4 v = *(const float4*)src;
        short4v s;
        s.x = (short)f2bf(v.x); s.y = (short)f2bf(v.y);
        s.z = (short)f2bf(v.z); s.w = (short)f2bf(v.w);
        *(short4v*)&wcomb[i] = s;
    } else {
        int idx = (bx - 80) * 256 + threadIdx.x;   // < 48*576 = 27648
        if (idx < 48 * 576) {
            int e = idx / 576;
            int k = idx - e * 576;
            int tap = k >> 6, c = k & 63;
            float v = (e < E_) ? we[((size_t)e * 64 + c) * 9 + tap] : 0.f;
            wBT[idx] = f2bf(v);
        }
    }
}

// ---------------- Kernel 1 (fused): [G; t] = wcomb @ x (bf16 MFMA) ----------------
// grid 1024 = n(4) * pxblk(256 of 64 px); 512 thr = 8 waves (4M x 2N), wave tile 80x32.
// A-frags straight from L2-hot wcomb (reg-prefetched); B in LDS dbuf;
// 2-deep x prefetch (nontemporal); 1 barrier/chunk. acc[5][2]=40 regs -> 2 blocks/CU.
__global__ __launch_bounds__(512, 4) void k_gemm(
    const float* __restrict__ x, const short* __restrict__ wcomb,
    const float* __restrict__ bd,
    unsigned short* __restrict__ Gq, unsigned short* __restrict__ t)
{
    __shared__ short Bsm[2][64 * 40];    // 2 x 5.1 KB

    int tid = threadIdx.x;
    int bx = blockIdx.x;
    int n = bx >> 8;
    int px0 = (bx & 255) * 64;

    int lane = tid & 63;
    int wave = tid >> 6;
    int wm = wave >> 1, wn = wave & 1;

    int bpx = tid & 63, bcq = tid >> 6;  // B stage role: px, 4-ch group (8 groups)
    const float* xb = x + (size_t)n * C_ * HW_ + px0 + bpx;

    int aoff[5];
    #pragma unroll
    for (int fm = 0; fm < 5; fm++) {
        int row = wm * 80 + fm * 16 + (lane & 15);
        aoff[fm] = row * 256 + ((lane >> 4) << 3);
    }

    float xs[2][4];
    short8 aw[5], an[5];

    auto xload = [&](int c0, int slot) {
        #pragma unroll
        for (int j = 0; j < 4; j++)
            xs[slot][j] = __builtin_nontemporal_load(&xb[(size_t)(c0 + bcq * 4 + j) * HW_]);
    };
    auto commit = [&](int buf, int slot) {
        short4v bv;
        bv.x = (short)f2bf(xs[slot][0]);
        bv.y = (short)f2bf(xs[slot][1]);
        bv.z = (short)f2bf(xs[slot][2]);
        bv.w = (short)f2bf(xs[slot][3]);
        *(short4v*)&Bsm[buf][bpx * 40 + bcq * 4] = bv;
    };

    floatx4 acc[5][2];
    #pragma unroll
    for (int fm = 0; fm < 5; fm++) {
        acc[fm][0] = (floatx4)0.f;
        acc[fm][1] = (floatx4)0.f;
    }

    xload(0, 0);
    #pragma unroll
    for (int fm = 0; fm < 5; fm++)
        aw[fm] = *(const short8*)&wcomb[aoff[fm]];
    commit(0, 0);
    xload(32, 1);
    __syncthreads();

    #pragma unroll
    for (int kc = 0; kc < 8; kc++) {
        int cur = kc & 1;
        if (kc < 6) xload((kc + 2) * 32, kc & 1);
        if (kc < 7) {
            #pragma unroll
            for (int fm = 0; fm < 5; fm++)
                an[fm] = *(const short8*)&wcomb[aoff[fm] + (kc + 1) * 32];
        }
        #pragma unroll
        for (int fn = 0; fn < 2; fn++) {
            int col = wn * 32 + fn * 16 + (lane & 15);
            short8 bf = *(const short8*)&Bsm[cur][col * 40 + (lane >> 4) * 8];
            #pragma unroll
            for (int fm = 0; fm < 5; fm++)
                acc[fm][fn] = __builtin_amdgcn_mfma_f32_16x16x32_bf16(aw[fm], bf, acc[fm][fn], 0, 0, 0);
        }
        if (kc < 7) {
            commit(cur ^ 1, (kc + 1) & 1);
            #pragma unroll
            for (int fm = 0; fm < 5; fm++) aw[fm] = an[fm];
            __syncthreads();
        }
    }

    #pragma unroll
    for (int fm = 0; fm < 5; fm++) {
        int row0 = wm * 80 + fm * 16;
        if (row0 < 256) {
            int oq = (row0 >> 2) + (lane >> 4);
            #pragma unroll
            for (int fn = 0; fn < 2; fn++) {
                int col = px0 + wn * 32 + fn * 16 + (lane & 15);
                ushort4v v;
                v.x = f2bf(acc[fm][fn][0]);
                v.y = f2bf(acc[fm][fn][1]);
                v.z = f2bf(acc[fm][fn][2]);
                v.w = f2bf(acc[fm][fn][3]);
                *(ushort4v*)&Gq[(((size_t)n * 64 + oq) * HW_ + col) * 4] = v;
            }
        } else {
            int ot = row0 - 256 + ((lane >> 4) << 2);
            float b0 = bd[ot + 0], b1 = bd[ot + 1], b2 = bd[ot + 2], b3 = bd[ot + 3];
            #pragma unroll
            for (int fn = 0; fn < 2; fn++) {
                int col = px0 + wn * 32 + fn * 16 + (lane & 15);
                ushort4v r;
                r.x = f2bf(acc[fm][fn][0] + b0);
                r.y = f2bf(acc[fm][fn][1] + b1);
                r.z = f2bf(acc[fm][fn][2] + b2);
                r.w = f2bf(acc[fm][fn][3] + b3);
                *(ushort4v*)&t[((size_t)n * HW_ + col) * 64 + ot] = r;
            }
        }
    }
}

// ---------------- Kernel 2: enc conv as MFMA GEMM + softmax (2-row blocks) ----------------
// grid 256 = n(4)*hb(64); 512 thr = 8 waves (waves 0-3 row h0, 4-7 row h0+1);
// wave M=32 px (2 m-frags), N=48, K=576. Halo 4 rows (vs 6 for two 1-row blocks).
// Tl = [4][130][64] bf16 XOR-swizzled (66.6 KB); El (256px x 49 f32) overlaid.
__global__ __launch_bounds__(512) void k_enc(
    const unsigned short* __restrict__ t, const unsigned short* __restrict__ wBT,
    const float* __restrict__ be, unsigned short* __restrict__ kernb)
{
    __shared__ short Tl[520 * 64];           // 66.6 KB ; El overlaid after barrier
    float* El = (float*)Tl;

    int bx = blockIdx.x;
    int n = bx >> 6, hb = bx & 63;
    int h0 = hb * 2;
    int tid = threadIdx.x;
    int lane = tid & 63, wave = tid >> 6;
    int ri = wave >> 2, wq = wave & 3;       // row-in-pair, px strip

    // 3-deep rotating b-frag prefetch (distance 2)
    short8 bpre[3][3];
    const unsigned short* wB0 = wBT + (size_t)(lane & 15) * 576 + (lane >> 4) * 8;
    #pragma unroll
    for (int p = 0; p < 2; p++)
        #pragma unroll
        for (int fn = 0; fn < 3; fn++)
            bpre[p][fn] = *(const short8*)(wB0 + fn * 16 * 576 + p * 32);

    // stage t halo: 4 rows (h0-1 .. h0+2), rows r = dr*130 + (ww+1)
    for (int idx = tid; idx < 4160; idx += 512) {
        int r = idx >> 3, ch = idx & 7;
        int dr = r / 130, rr = r - dr * 130;
        int hh = h0 + dr - 1, ww = rr - 1;
        short8 v = {0,0,0,0,0,0,0,0};
        if (hh >= 0 && hh < H_ && ww >= 0 && ww < W_)
            v = *(const short8*)&t[((size_t)(n * H_ + hh) * W_ + ww) * 64 + ch * 8];
        int us = (r * 64 + ch * 8) ^ ((r & 7) << 3);
        *(short8*)&Tl[us] = v;
    }
    __syncthreads();

    floatx4 acc[2][3];
    #pragma unroll
    for (int mf = 0; mf < 2; mf++)
        #pragma unroll
        for (int fn = 0; fn < 3; fn++)
            acc[mf][fn] = (floatx4)0.f;

    int pxw = wq * 32 + (lane & 15);         // px within row; +16 for m-frag 1
    int kq = (lane >> 4) * 8;

    __builtin_amdgcn_s_setprio(1);
    #pragma unroll
    for (int kc = 0; kc < 18; kc++) {
        if (kc < 16) {
            int slot = (kc + 2) % 3;
            #pragma unroll
            for (int fn = 0; fn < 3; fn++)
                bpre[slot][fn] = *(const short8*)(wB0 + fn * 16 * 576 + (kc + 2) * 32);
        }
        const int cur = kc % 3;
        const int tap = kc >> 1, chalf = kc & 1;
        const int di = tap / 3, dj = tap % 3;
        #pragma unroll
        for (int mf = 0; mf < 2; mf++) {
            int r = (ri + di) * 130 + pxw + mf * 16 + dj;
            int us = (r * 64 + chalf * 32 + kq) ^ ((r & 7) << 3);
            short8 af = *(const short8*)&Tl[us];
            #pragma unroll
            for (int fn = 0; fn < 3; fn++)
                acc[mf][fn] = __builtin_amdgcn_mfma_f32_16x16x32_bf16(af, bpre[cur][fn], acc[mf][fn], 0, 0, 0);
        }
    }
    __builtin_amdgcn_s_setprio(0);
    __syncthreads();   // all waves done reading Tl -> safe to overlay El

    #pragma unroll
    for (int mf = 0; mf < 2; mf++)
        #pragma unroll
        for (int fn = 0; fn < 3; fn++)
            #pragma unroll
            for (int i = 0; i < 4; i++) {
                int px = ri * 128 + wq * 32 + mf * 16 + (lane >> 4) * 4 + i;
                El[px * 49 + fn * 16 + (lane & 15)] = acc[mf][fn][i];
            }
    __syncthreads();

    // softmax: thread -> (sp = tid>>1 in 0..255, two q's); bf16 plane writes
    int sp = tid >> 1;
    int pxg = n * HW_ + (h0 + (sp >> 7)) * W_ + (sp & 127);
    #pragma unroll
    for (int qq = 0; qq < 2; qq++) {
        int q = (tid & 1) * 2 + qq;
        float l[9];
        #pragma unroll
        for (int k = 0; k < 9; k++) l[k] = El[sp * 49 + k * 4 + q] + be[k * 4 + q];
        float m = l[0];
        #pragma unroll
        for (int k = 1; k < 9; k++) m = fmaxf(m, l[k]);
        float ex[9], s = 0.f;
        #pragma unroll
        for (int k = 0; k < 9; k++) { ex[k] = __expf(l[k] - m); s += ex[k]; }
        float inv = 1.f / s;
        #pragma unroll
        for (int k = 0; k < 9; k++)
            kernb[(size_t)(k * 4 + q) * NPX_ + pxg] = f2bf(ex[k] * inv);
    }
}

// ---------------- Kernel 3: 9-tap combine + pixel shuffle + bias ----------------
// grid 2048; bx = (n*64 + og*8 + hbhi)*8 + (hb&7) -> og-siblings same XCD.
// y stores nontemporal; kern loads nontemporal (read-once).
__global__ __launch_bounds__(256) void k_up(
    const unsigned short* __restrict__ Gq, const unsigned short* __restrict__ kernb,
    const float* __restrict__ bo, float* __restrict__ y)
{
    int bx = blockIdx.x;
    int x7 = bx & 7;
    int g  = bx >> 3;
    int hbhi = g & 7;
    int og = (g >> 3) & 7;
    int n  = g >> 6;
    int hb = hbhi * 8 + x7;

    int tid = threadIdx.x;
    int h = hb * 2 + (tid >> 7);
    int w = tid & 127;
    int idxp = n * HW_ + h * W_ + w;

    float kv[36];
    #pragma unroll
    for (int e = 0; e < E_; e++)
        kv[e] = bf2f(__builtin_nontemporal_load(&kernb[(size_t)e * NPX_ + idxp]));

    int off[9]; bool val[9];
    #pragma unroll
    for (int di = 0; di < 3; di++) {
        int hh = h + di - 1;
        bool hvv = (hh >= 0 && hh < H_);
        int hc = hvv ? hh : h;
        #pragma unroll
        for (int dj = 0; dj < 3; dj++) {
            int ww = w + dj - 1;
            bool wvv = (ww >= 0 && ww < W_);
            int wc = wvv ? ww : w;
            off[di * 3 + dj] = hc * W_ + wc;
            val[di * 3 + dj] = hvv && wvv;
        }
    }

    const unsigned short* Gb = Gq + ((size_t)n * 64 + og * 8) * HW_ * 4;
    size_t ybase = ((size_t)n * OC_ + og * 32) * (4 * HW_) + (size_t)(2 * h) * 256 + 2 * w;

    #pragma unroll 2
    for (int j = 0; j < 8; j++) {
        const unsigned short* Gj = Gb + (size_t)j * HW_ * 4;
        float b0 = bo[og * 32 + j * 4 + 0];
        float b1 = bo[og * 32 + j * 4 + 1];
        float b2 = bo[og * 32 + j * 4 + 2];
        float b3 = bo[og * 32 + j * 4 + 3];
        float a[4][4];
        #pragma unroll
        for (int s = 0; s < 4; s++) { a[0][s] = b0; a[1][s] = b1; a[2][s] = b2; a[3][s] = b3; }
        #pragma unroll
        for (int k = 0; k < 9; k++) {
            ushort4v gv = *(const ushort4v*)(Gj + (size_t)off[k] * 4);
            float g0 = val[k] ? bf2f(gv.x) : 0.f;
            float g1 = val[k] ? bf2f(gv.y) : 0.f;
            float g2 = val[k] ? bf2f(gv.z) : 0.f;
            float g3 = val[k] ? bf2f(gv.w) : 0.f;
            #pragma unroll
            for (int s = 0; s < 4; s++) {
                float kw = kv[k * 4 + s];
                a[0][s] = fmaf(g0, kw, a[0][s]);
                a[1][s] = fmaf(g1, kw, a[1][s]);
                a[2][s] = fmaf(g2, kw, a[2][s]);
                a[3][s] = fmaf(g3, kw, a[3][s]);
            }
        }
        #pragma unroll
        for (int i = 0; i < 4; i++) {
            float* yp = y + ybase + (size_t)(j * 4 + i) * (4 * HW_);
            floatx2 r0; r0.x = a[i][0]; r0.y = a[i][1];
            floatx2 r1; r1.x = a[i][2]; r1.y = a[i][3];
            __builtin_nontemporal_store(r0, (floatx2*)yp);
            __builtin_nontemporal_store(r1, (floatx2*)(yp + 256));
        }
    }
}

extern "C" void kernel_launch(void* const* d_in, const int* in_sizes, int n_in,
                              void* d_out, int out_size, void* d_ws, size_t ws_size,
                              hipStream_t stream) {
    const float* x  = (const float*)d_in[0];
    const float* wd = (const float*)d_in[1];
    const float* bd = (const float*)d_in[2];
    const float* we = (const float*)d_in[3];
    const float* be = (const float*)d_in[4];
    const float* wo = (const float*)d_in[5];
    const float* bo = (const float*)d_in[6];
    float* y = (float*)d_out;

    unsigned short* t = (unsigned short*)d_ws;                 // [NPX][64] bf16 = 8.4 MB
    unsigned short* kernb = t + (size_t)NPX_ * 64;             // [36][NPX] bf16 = 4.7 MB
    short* wcomb = (short*)(kernb + (size_t)E_ * NPX_);        // [320][256] bf16
    unsigned short* wBT = (unsigned short*)(wcomb + (size_t)320 * C_);  // [48][576] bf16
    unsigned short* Gq  = wBT + (size_t)48 * 576;              // 33.5 MB

    k_prep<<<188,  256, 0, stream>>>(wo, wd, wcomb, we, wBT);
    k_gemm<<<1024, 512, 0, stream>>>(x, wcomb, bd, Gq, t);
    k_enc <<<256,  512, 0, stream>>>(t, wBT, be, kernb);
    k_up  <<<2048, 256, 0, stream>>>(Gq, kernb, bo, y);
}

// Round 16
// 131.056 us; speedup vs baseline: 1.1161x; 1.1161x over previous
//
#include <hip/hip_runtime.h>
#include <hip/hip_bf16.h>
#include <stddef.h>

typedef __attribute__((ext_vector_type(8))) short short8;
typedef __attribute__((ext_vector_type(4))) short short4v;
typedef __attribute__((ext_vector_type(4))) unsigned short ushort4v;
typedef __attribute__((ext_vector_type(4))) float floatx4;
typedef __attribute__((ext_vector_type(2))) float floatx2;

#define N_ 4
#define C_ 256
#define H_ 128
#define W_ 128
#define HW_ (H_*W_)
#define NPX_ (N_*HW_)   // 65536
#define E_ 36      // k2*up2
#define OC_ 256

// round-to-nearest-even f32 -> bf16 bits
static __device__ __forceinline__ unsigned short f2bf(float f) {
    union { float f; unsigned u; } v; v.f = f;
    unsigned r = v.u + 0x7fff + ((v.u >> 16) & 1);
    return (unsigned short)(r >> 16);
}
static __device__ __forceinline__ float bf2f(unsigned short s) {
    union { unsigned u; float f; } v; v.u = ((unsigned)s) << 16;
    return v.f;
}

// ---------------- Kernel 0: build wcomb[320][256] bf16 (w_out ++ w_down) ; wBT[48][576] bf16 ----------------
__global__ __launch_bounds__(256) void k_prep(const float* __restrict__ wo,
                                              const float* __restrict__ wd,
                                              short* __restrict__ wcomb,
                                              const float* __restrict__ we,
                                              unsigned short* __restrict__ wBT) {
    int bx = blockIdx.x;
    if (bx < 80) {
        int i = (bx * 256 + threadIdx.x) * 4;   // < 81920
        int row = i >> 8, c = i & 255;
        const float* src = (row < 256) ? &wo[row * 256 + c] : &wd[(row - 256) * 256 + c];
        float4 v = *(const float4*)src;
        short4v s;
        s.x = (short)f2bf(v.x); s.y = (short)f2bf(v.y);
        s.z = (short)f2bf(v.z); s.w = (short)f2bf(v.w);
        *(short4v*)&wcomb[i] = s;
    } else {
        int idx = (bx - 80) * 256 + threadIdx.x;   // < 48*576 = 27648
        if (idx < 48 * 576) {
            int e = idx / 576;
            int k = idx - e * 576;
            int tap = k >> 6, c = k & 63;
            float v = (e < E_) ? we[((size_t)e * 64 + c) * 9 + tap] : 0.f;
            wBT[idx] = f2bf(v);
        }
    }
}

// ---------------- Kernel 1 (fused): [G; t] = wcomb @ x (bf16 MFMA) ----------------
// grid 1024 = n(4) * pxblk(256 of 64 px); 512 thr = 8 waves (4M x 2N), wave tile 80x32.
// A-frags straight from L2-hot wcomb (reg-prefetched); B in LDS dbuf (10 KB total);
// 2-deep x prefetch; 1 barrier/chunk. acc[5][2]=40 regs -> 2 blocks/CU.
// x loads nontemporal (read-once stream, keep caches for wcomb/G).
__global__ __launch_bounds__(512, 4) void k_gemm(
    const float* __restrict__ x, const short* __restrict__ wcomb,
    const float* __restrict__ bd,
    unsigned short* __restrict__ Gq, unsigned short* __restrict__ t)
{
    __shared__ short Bsm[2][64 * 40];    // 2 x 5.1 KB

    int tid = threadIdx.x;
    int bx = blockIdx.x;
    int n = bx >> 8;
    int px0 = (bx & 255) * 64;

    int lane = tid & 63;
    int wave = tid >> 6;
    int wm = wave >> 1, wn = wave & 1;

    int bpx = tid & 63, bcq = tid >> 6;  // B stage role: px, 4-ch group (8 groups)
    const float* xb = x + (size_t)n * C_ * HW_ + px0 + bpx;

    // per-frag A element offsets (row*256 + kq*8), c0 added per chunk
    int aoff[5];
    #pragma unroll
    for (int fm = 0; fm < 5; fm++) {
        int row = wm * 80 + fm * 16 + (lane & 15);
        aoff[fm] = row * 256 + ((lane >> 4) << 3);
    }

    float xs[2][4];
    short8 aw[5], an[5];

    auto xload = [&](int c0, int slot) {
        #pragma unroll
        for (int j = 0; j < 4; j++)
            xs[slot][j] = __builtin_nontemporal_load(&xb[(size_t)(c0 + bcq * 4 + j) * HW_]);
    };
    auto commit = [&](int buf, int slot) {
        short4v bv;
        bv.x = (short)f2bf(xs[slot][0]);
        bv.y = (short)f2bf(xs[slot][1]);
        bv.z = (short)f2bf(xs[slot][2]);
        bv.w = (short)f2bf(xs[slot][3]);
        *(short4v*)&Bsm[buf][bpx * 40 + bcq * 4] = bv;
    };

    floatx4 acc[5][2];
    #pragma unroll
    for (int fm = 0; fm < 5; fm++) {
        acc[fm][0] = (floatx4)0.f;
        acc[fm][1] = (floatx4)0.f;
    }

    // prologue: chunk0 B staged; chunk1 x in flight; chunk0 A in regs
    xload(0, 0);
    #pragma unroll
    for (int fm = 0; fm < 5; fm++)
        aw[fm] = *(const short8*)&wcomb[aoff[fm]];
    commit(0, 0);
    xload(32, 1);
    __syncthreads();

    #pragma unroll
    for (int kc = 0; kc < 8; kc++) {
        int cur = kc & 1;
        if (kc < 6) xload((kc + 2) * 32, kc & 1);          // x for chunk kc+2
        if (kc < 7) {
            #pragma unroll
            for (int fm = 0; fm < 5; fm++)                  // A for chunk kc+1
                an[fm] = *(const short8*)&wcomb[aoff[fm] + (kc + 1) * 32];
        }
        #pragma unroll
        for (int fn = 0; fn < 2; fn++) {
            int col = wn * 32 + fn * 16 + (lane & 15);
            short8 bf = *(const short8*)&Bsm[cur][col * 40 + (lane >> 4) * 8];
            #pragma unroll
            for (int fm = 0; fm < 5; fm++)
                acc[fm][fn] = __builtin_amdgcn_mfma_f32_16x16x32_bf16(aw[fm], bf, acc[fm][fn], 0, 0, 0);
        }
        if (kc < 7) {
            commit(cur ^ 1, (kc + 1) & 1);                  // B for chunk kc+1
            #pragma unroll
            for (int fm = 0; fm < 5; fm++) aw[fm] = an[fm];
            __syncthreads();
        }
    }

    // epilogue: rows < 256 -> G o-quads; rows >= 256 -> t channel-last + bias
    #pragma unroll
    for (int fm = 0; fm < 5; fm++) {
        int row0 = wm * 80 + fm * 16;          // wave-uniform, multiple of 16
        if (row0 < 256) {
            int oq = (row0 >> 2) + (lane >> 4);
            #pragma unroll
            for (int fn = 0; fn < 2; fn++) {
                int col = px0 + wn * 32 + fn * 16 + (lane & 15);
                ushort4v v;
                v.x = f2bf(acc[fm][fn][0]);
                v.y = f2bf(acc[fm][fn][1]);
                v.z = f2bf(acc[fm][fn][2]);
                v.w = f2bf(acc[fm][fn][3]);
                *(ushort4v*)&Gq[(((size_t)n * 64 + oq) * HW_ + col) * 4] = v;
            }
        } else {
            int ot = row0 - 256 + ((lane >> 4) << 2);
            float b0 = bd[ot + 0], b1 = bd[ot + 1], b2 = bd[ot + 2], b3 = bd[ot + 3];
            #pragma unroll
            for (int fn = 0; fn < 2; fn++) {
                int col = px0 + wn * 32 + fn * 16 + (lane & 15);
                ushort4v r;
                r.x = f2bf(acc[fm][fn][0] + b0);
                r.y = f2bf(acc[fm][fn][1] + b1);
                r.z = f2bf(acc[fm][fn][2] + b2);
                r.w = f2bf(acc[fm][fn][3] + b3);
                *(ushort4v*)&t[((size_t)n * HW_ + col) * 64 + ot] = r;
            }
        }
    }
}

// ---------------- Kernel 2: enc conv as MFMA GEMM + softmax (full-row blocks) ----------------
// grid 512 = n(4)*h(128); 256 thr = 4 waves; wave M=32 px (2 m-frags), N=48, K=576.
// Tl = [3][130][64] bf16 XOR-swizzled (49.9 KB); El overlaid on Tl after barrier.
__global__ __launch_bounds__(256) void k_enc(
    const unsigned short* __restrict__ t, const unsigned short* __restrict__ wBT,
    const float* __restrict__ be, unsigned short* __restrict__ kernb)
{
    __shared__ short Tl[390 * 64];           // 49.9 KB ; El (float, stride 49) overlaid
    float* El = (float*)Tl;

    int bx = blockIdx.x;
    int n = bx >> 7, h = bx & 127;
    int tid = threadIdx.x;
    int lane = tid & 63, wave = tid >> 6;

    // 3-deep rotating b-frag prefetch (distance 2)
    short8 bpre[3][3];
    const unsigned short* wB0 = wBT + (size_t)(lane & 15) * 576 + (lane >> 4) * 8;
    #pragma unroll
    for (int p = 0; p < 2; p++)
        #pragma unroll
        for (int fn = 0; fn < 3; fn++)
            bpre[p][fn] = *(const short8*)(wB0 + fn * 16 * 576 + p * 32);

    // stage t halo: rows r = di*130 + (ww+1), 64 ch each
    for (int idx = tid; idx < 3120; idx += 256) {
        int r = idx >> 3, ch = idx & 7;
        int di = r / 130, rr = r - di * 130;
        int hh = h + di - 1, ww = rr - 1;
        short8 v = {0,0,0,0,0,0,0,0};
        if (hh >= 0 && hh < H_ && ww >= 0 && ww < W_)
            v = *(const short8*)&t[((size_t)(n * H_ + hh) * W_ + ww) * 64 + ch * 8];
        int us = (r * 64 + ch * 8) ^ ((r & 7) << 3);
        *(short8*)&Tl[us] = v;
    }
    __syncthreads();

    floatx4 acc[2][3];
    #pragma unroll
    for (int mf = 0; mf < 2; mf++)
        #pragma unroll
        for (int fn = 0; fn < 3; fn++)
            acc[mf][fn] = (floatx4)0.f;

    int pxw = wave * 32 + (lane & 15);   // m-frag 0 row; +16 for m-frag 1
    int kq = (lane >> 4) * 8;

    #pragma unroll
    for (int kc = 0; kc < 18; kc++) {
        if (kc < 16) {
            int slot = (kc + 2) % 3;
            #pragma unroll
            for (int fn = 0; fn < 3; fn++)
                bpre[slot][fn] = *(const short8*)(wB0 + fn * 16 * 576 + (kc + 2) * 32);
        }
        const int cur = kc % 3;
        const int tap = kc >> 1, chalf = kc & 1;
        const int di = tap / 3, dj = tap % 3;
        #pragma unroll
        for (int mf = 0; mf < 2; mf++) {
            int r = di * 130 + pxw + mf * 16 + dj;
            int us = (r * 64 + chalf * 32 + kq) ^ ((r & 7) << 3);
            short8 af = *(const short8*)&Tl[us];
            #pragma unroll
            for (int fn = 0; fn < 3; fn++)
                acc[mf][fn] = __builtin_amdgcn_mfma_f32_16x16x32_bf16(af, bpre[cur][fn], acc[mf][fn], 0, 0, 0);
        }
    }
    __syncthreads();   // all waves done reading Tl -> safe to overlay El

    #pragma unroll
    for (int mf = 0; mf < 2; mf++)
        #pragma unroll
        for (int fn = 0; fn < 3; fn++)
            #pragma unroll
            for (int i = 0; i < 4; i++) {
                int px = wave * 32 + mf * 16 + (lane >> 4) * 4 + i;
                El[px * 49 + fn * 16 + (lane & 15)] = acc[mf][fn][i];
            }
    __syncthreads();

    // softmax: thread -> (sp = tid>>1, two q's); bf16 plane writes
    int sp = tid >> 1;
    int pxg = n * HW_ + h * W_ + sp;
    #pragma unroll
    for (int qq = 0; qq < 2; qq++) {
        int q = (tid & 1) * 2 + qq;
        float l[9];
        #pragma unroll
        for (int k = 0; k < 9; k++) l[k] = El[sp * 49 + k * 4 + q] + be[k * 4 + q];
        float m = l[0];
        #pragma unroll
        for (int k = 1; k < 9; k++) m = fmaxf(m, l[k]);
        float ex[9], s = 0.f;
        #pragma unroll
        for (int k = 0; k < 9; k++) { ex[k] = __expf(l[k] - m); s += ex[k]; }
        float inv = 1.f / s;
        #pragma unroll
        for (int k = 0; k < 9; k++)
            kernb[(size_t)(k * 4 + q) * NPX_ + pxg] = f2bf(ex[k] * inv);
    }
}

// ---------------- Kernel 3: 9-tap combine + pixel shuffle + bias ----------------
// grid 2048; bx = (n*64 + og*8 + hbhi)*8 + (hb&7) -> og-siblings same XCD.
// y stores nontemporal (pure streaming output, keep L2/L3 for G/kern).
__global__ __launch_bounds__(256) void k_up(
    const unsigned short* __restrict__ Gq, const unsigned short* __restrict__ kernb,
    const float* __restrict__ bo, float* __restrict__ y)
{
    int bx = blockIdx.x;
    int x7 = bx & 7;
    int g  = bx >> 3;
    int hbhi = g & 7;
    int og = (g >> 3) & 7;
    int n  = g >> 6;
    int hb = hbhi * 8 + x7;

    int tid = threadIdx.x;
    int h = hb * 2 + (tid >> 7);
    int w = tid & 127;
    int idxp = n * HW_ + h * W_ + w;

    float kv[36];
    #pragma unroll
    for (int e = 0; e < E_; e++)
        kv[e] = bf2f(kernb[(size_t)e * NPX_ + idxp]);

    int off[9]; bool val[9];
    #pragma unroll
    for (int di = 0; di < 3; di++) {
        int hh = h + di - 1;
        bool hvv = (hh >= 0 && hh < H_);
        int hc = hvv ? hh : h;
        #pragma unroll
        for (int dj = 0; dj < 3; dj++) {
            int ww = w + dj - 1;
            bool wvv = (ww >= 0 && ww < W_);
            int wc = wvv ? ww : w;
            off[di * 3 + dj] = hc * W_ + wc;
            val[di * 3 + dj] = hvv && wvv;
        }
    }

    const unsigned short* Gb = Gq + ((size_t)n * 64 + og * 8) * HW_ * 4;
    size_t ybase = ((size_t)n * OC_ + og * 32) * (4 * HW_) + (size_t)(2 * h) * 256 + 2 * w;

    #pragma unroll 2
    for (int j = 0; j < 8; j++) {
        const unsigned short* Gj = Gb + (size_t)j * HW_ * 4;
        float b0 = bo[og * 32 + j * 4 + 0];
        float b1 = bo[og * 32 + j * 4 + 1];
        float b2 = bo[og * 32 + j * 4 + 2];
        float b3 = bo[og * 32 + j * 4 + 3];
        float a[4][4];
        #pragma unroll
        for (int s = 0; s < 4; s++) { a[0][s] = b0; a[1][s] = b1; a[2][s] = b2; a[3][s] = b3; }
        #pragma unroll
        for (int k = 0; k < 9; k++) {
            ushort4v gv = *(const ushort4v*)(Gj + (size_t)off[k] * 4);
            float g0 = val[k] ? bf2f(gv.x) : 0.f;
            float g1 = val[k] ? bf2f(gv.y) : 0.f;
            float g2 = val[k] ? bf2f(gv.z) : 0.f;
            float g3 = val[k] ? bf2f(gv.w) : 0.f;
            #pragma unroll
            for (int s = 0; s < 4; s++) {
                float kw = kv[k * 4 + s];
                a[0][s] = fmaf(g0, kw, a[0][s]);
                a[1][s] = fmaf(g1, kw, a[1][s]);
                a[2][s] = fmaf(g2, kw, a[2][s]);
                a[3][s] = fmaf(g3, kw, a[3][s]);
            }
        }
        #pragma unroll
        for (int i = 0; i < 4; i++) {
            float* yp = y + ybase + (size_t)(j * 4 + i) * (4 * HW_);
            floatx2 r0; r0.x = a[i][0]; r0.y = a[i][1];
            floatx2 r1; r1.x = a[i][2]; r1.y = a[i][3];
            __builtin_nontemporal_store(r0, (floatx2*)yp);
            __builtin_nontemporal_store(r1, (floatx2*)(yp + 256));
        }
    }
}

extern "C" void kernel_launch(void* const* d_in, const int* in_sizes, int n_in,
                              void* d_out, int out_size, void* d_ws, size_t ws_size,
                              hipStream_t stream) {
    const float* x  = (const float*)d_in[0];
    const float* wd = (const float*)d_in[1];
    const float* bd = (const float*)d_in[2];
    const float* we = (const float*)d_in[3];
    const float* be = (const float*)d_in[4];
    const float* wo = (const float*)d_in[5];
    const float* bo = (const float*)d_in[6];
    float* y = (float*)d_out;

    unsigned short* t = (unsigned short*)d_ws;                 // [NPX][64] bf16 = 8.4 MB
    unsigned short* kernb = t + (size_t)NPX_ * 64;             // [36][NPX] bf16 = 4.7 MB
    short* wcomb = (short*)(kernb + (size_t)E_ * NPX_);        // [320][256] bf16
    unsigned short* wBT = (unsigned short*)(wcomb + (size_t)320 * C_);  // [48][576] bf16
    unsigned short* Gq  = wBT + (size_t)48 * 576;              // 33.5 MB

    k_prep<<<188,  256, 0, stream>>>(wo, wd, wcomb, we, wBT);
    k_gemm<<<1024, 512, 0, stream>>>(x, wcomb, bd, Gq, t);
    k_enc <<<512,  256, 0, stream>>>(t, wBT, be, kernb);
    k_up  <<<2048, 256, 0, stream>>>(Gq, kernb, bo, y);
}